// Round 2
// baseline (960.323 us; speedup 1.0000x reference)
//
#include <hip/hip_runtime.h>
#include <hip/hip_bf16.h>
#include <cstdint>

// BN(train) -> sign -> conv3x3(sign(w), pad=1) -> +b -> relu, as XNOR-popcount conv.
// y = 256*V - 2*D + 2*corr, D = popcount over zero-padded packed bits.

#define N_IMG 64
#define C_CH 256
#define HW 3136
#define W_IMG 56
#define NSLICE 16   // 4 images per slice

// ---------------- Kernel A1: partial per-channel sums (deterministic) ----------------
__global__ void stats_part(const float* __restrict__ x, double2* __restrict__ partial) {
    const int c = blockIdx.x;      // 256
    const int sl = blockIdx.y;     // 16
    const int tid = threadIdx.x;   // 256
    float s = 0.f, q = 0.f;
    for (int n = sl * 4; n < sl * 4 + 4; ++n) {
        const float4* xn = (const float4*)(x + ((size_t)n * C_CH + c) * HW);
        for (int i = tid; i < HW / 4; i += 256) {
            float4 v = xn[i];
            s += (v.x + v.y) + (v.z + v.w);
            q = fmaf(v.x, v.x, q); q = fmaf(v.y, v.y, q);
            q = fmaf(v.z, v.z, q); q = fmaf(v.w, v.w, q);
        }
    }
    double ds = (double)s, dq = (double)q;
#pragma unroll
    for (int off = 32; off > 0; off >>= 1) {
        ds += __shfl_down(ds, off);
        dq += __shfl_down(dq, off);
    }
    __shared__ double sh[4][2];
    int wid = tid >> 6;
    if ((tid & 63) == 0) { sh[wid][0] = ds; sh[wid][1] = dq; }
    __syncthreads();
    if (tid == 0) {
        double S = sh[0][0] + sh[1][0] + sh[2][0] + sh[3][0];
        double Q = sh[0][1] + sh[1][1] + sh[2][1] + sh[3][1];
        partial[sl * C_CH + c] = make_double2(S, Q);
    }
}

// ---------------- Kernel A2: finalize BN fold ----------------
__global__ void stats_final(const double2* __restrict__ partial,
                            const float* __restrict__ gamma, const float* __restrict__ beta,
                            float* __restrict__ scaleA, float* __restrict__ biasC) {
    int c = threadIdx.x;   // 256, one block
    double S = 0.0, Q = 0.0;
#pragma unroll
    for (int sl = 0; sl < NSLICE; ++sl) {
        double2 p = partial[sl * C_CH + c];
        S += p.x; Q += p.y;
    }
    const double M = (double)N_IMG * (double)HW;
    double mean = S / M;
    double var = Q / M - mean * mean;
    float inv = (float)(1.0 / sqrt(var + 1e-5));
    float a = gamma[c] * inv;
    scaleA[c] = a;
    biasC[c] = beta[c] - (float)mean * a;
}

// ---------------- Kernel C: pack sign(w) + per-tap popcounts ----------------
__global__ void wpack_kernel(const float* __restrict__ w, uint32_t* __restrict__ wpack,
                             int* __restrict__ wtap) {
    int id = blockIdx.x * 256 + threadIdx.x;   // 2304 = 256 co * 9 taps
    if (id >= 2304) return;
    int co = id / 9, t = id - co * 9;
    const float* wp = w + (size_t)co * 2304 + t;   // w[co][ci][t], ci stride 9
    int pc = 0;
#pragma unroll
    for (int wd = 0; wd < 8; ++wd) {
        uint32_t bits = 0;
        for (int i = 0; i < 32; ++i) {
            float v = wp[(size_t)(wd * 32 + i) * 9];
            bits |= (v > 0.f ? (1u << i) : 0u);
        }
        wpack[(size_t)id * 8 + wd] = bits;
        pc += __popc(bits);
    }
    wtap[id] = pc;
}

// ---------------- Kernel B: binarize + pack, 4 pixels per thread ----------------
// apack layout: [n][y][x][8 x u32]  (32B per pixel)
__global__ void binarize_kernel(const float* __restrict__ x, const float* __restrict__ A,
                                const float* __restrict__ C, uint32_t* __restrict__ apack) {
    int t = blockIdx.x * 128 + threadIdx.x;    // 50176 threads = 200704/4
    int n = t / (HW / 4);
    int r4 = t - n * (HW / 4);                 // float4 index within image
    const float4* xp = (const float4*)(x + (size_t)n * C_CH * HW) + r4;
    uint32_t bits[4][8];
#pragma unroll
    for (int wo = 0; wo < 8; ++wo) {
        uint32_t b0 = 0, b1 = 0, b2 = 0, b3 = 0;
#pragma unroll
        for (int i = 0; i < 32; ++i) {
            int c = wo * 32 + i;
            float4 v = xp[(size_t)c * (HW / 4)];
            float a = A[c], cc = C[c];
            b0 |= (fmaf(a, v.x, cc) > 0.f ? (1u << i) : 0u);
            b1 |= (fmaf(a, v.y, cc) > 0.f ? (1u << i) : 0u);
            b2 |= (fmaf(a, v.z, cc) > 0.f ? (1u << i) : 0u);
            b3 |= (fmaf(a, v.w, cc) > 0.f ? (1u << i) : 0u);
        }
        bits[0][wo] = b0; bits[1][wo] = b1; bits[2][wo] = b2; bits[3][wo] = b3;
    }
    size_t p0 = (size_t)n * HW + (size_t)r4 * 4;
#pragma unroll
    for (int k = 0; k < 4; ++k) {
        uint4* dst = (uint4*)(apack + (p0 + k) * 8);
        dst[0] = make_uint4(bits[k][0], bits[k][1], bits[k][2], bits[k][3]);
        dst[1] = make_uint4(bits[k][4], bits[k][5], bits[k][6], bits[k][7]);
    }
}

// ---------------- Kernel D: XNOR-popcount conv (tap-outer, co-inner) ----------------
#define COG 8
__global__ __launch_bounds__(256, 6) void conv_kernel(
    const uint32_t* __restrict__ apack, const uint32_t* __restrict__ wpack,
    const int* __restrict__ wtap, const float* __restrict__ bias,
    float* __restrict__ out) {
    const int xt = blockIdx.x, yt = blockIdx.y;
    const int z = blockIdx.z;
    const int n = z >> 5;      // /32
    const int cg = z & 31;
    const int tid = threadIdx.x;
    const int tx = tid & 31, ty = tid >> 5;
    const int gx0 = xt * 32, gy0 = yt * 8;

    // halo: 10 rows x 34 cols x 32B = 10880B
    __shared__ __align__(16) uint32_t lds[10 * 34 * 8];
    const int HP = 10 * 34;
    for (int i = tid; i < HP * 2; i += 256) {
        int pix = i >> 1, h = i & 1;
        int r = pix / 34, c0 = pix - r * 34;
        int gy = gy0 - 1 + r, gx = gx0 - 1 + c0;
        uint4 v = make_uint4(0u, 0u, 0u, 0u);
        if (gy >= 0 && gy < W_IMG && gx >= 0 && gx < W_IMG) {
            const uint4* src = (const uint4*)(apack + ((size_t)(n * HW + gy * W_IMG + gx)) * 8);
            v = src[h];
        }
        ((uint4*)lds)[pix * 2 + h] = v;
    }
    __syncthreads();

    const uint64_t* l64 = (const uint64_t*)lds;
    const uint64_t* w64 = (const uint64_t*)wpack + (size_t)cg * COG * 9 * 4;

    int acc[COG];
#pragma unroll
    for (int co = 0; co < COG; ++co) acc[co] = 0;

#pragma unroll
    for (int dy = 0; dy < 3; ++dy) {
#pragma unroll
        for (int dx = 0; dx < 3; ++dx) {
            const int t = dy * 3 + dx;
            const int p = (ty + dy) * 34 + (tx + dx);
            uint64_t a0 = l64[p * 4 + 0];
            uint64_t a1 = l64[p * 4 + 1];
            uint64_t a2 = l64[p * 4 + 2];
            uint64_t a3 = l64[p * 4 + 3];
#pragma unroll
            for (int co = 0; co < COG; ++co) {
                const uint64_t* wp = w64 + (size_t)(co * 9 + t) * 4;
                int s = acc[co];
                s += __popcll(a0 ^ wp[0]);
                s += __popcll(a1 ^ wp[1]);
                s += __popcll(a2 ^ wp[2]);
                s += __popcll(a3 ^ wp[3]);
                acc[co] = s;
            }
        }
    }

    const int gx = gx0 + tx, gy = gy0 + ty;   // gy < 56 always (7*8)
    if (gx >= W_IMG) return;

    int vy = 3 - (gy == 0) - (gy == W_IMG - 1);
    int vx = 3 - (gx == 0) - (gx == W_IMG - 1);
    int V = vy * vx;

    int corr[COG];
#pragma unroll
    for (int co = 0; co < COG; ++co) corr[co] = 0;
    if (V != 9) {
#pragma unroll
        for (int t = 0; t < 9; ++t) {
            int dy = t / 3 - 1, dx = t % 3 - 1;
            bool inv = (gy + dy < 0) || (gy + dy > W_IMG - 1) || (gx + dx < 0) || (gx + dx > W_IMG - 1);
            if (inv) {
#pragma unroll
                for (int co = 0; co < COG; ++co) corr[co] += wtap[(cg * COG + co) * 9 + t];
            }
        }
    }

#pragma unroll
    for (int co = 0; co < COG; ++co) {
        int cofull = cg * COG + co;
        float y = (float)(256 * V - 2 * acc[co] + 2 * corr[co]) + bias[cofull];
        out[((size_t)(n * C_CH + cofull)) * HW + gy * W_IMG + gx] = fmaxf(y, 0.f);
    }
}

extern "C" void kernel_launch(void* const* d_in, const int* in_sizes, int n_in,
                              void* d_out, int out_size, void* d_ws, size_t ws_size,
                              hipStream_t stream) {
    const float* x     = (const float*)d_in[0];
    const float* gamma = (const float*)d_in[1];
    const float* beta  = (const float*)d_in[2];
    const float* w     = (const float*)d_in[3];
    const float* b     = (const float*)d_in[4];
    float* out = (float*)d_out;

    char* ws = (char*)d_ws;
    float*    scaleA  = (float*)(ws);                 // 256 f
    float*    biasC   = (float*)(ws + 1024);          // 256 f
    uint32_t* wpack   = (uint32_t*)(ws + 2048);       // 73728 B
    int*      wtap    = (int*)(ws + 75776);           // 9216 B
    double2*  partial = (double2*)(ws + 131072);      // 65536 B
    uint32_t* apack   = (uint32_t*)(ws + 262144);     // 6.4 MB

    stats_part<<<dim3(C_CH, NSLICE), 256, 0, stream>>>(x, partial);
    stats_final<<<1, C_CH, 0, stream>>>(partial, gamma, beta, scaleA, biasC);
    wpack_kernel<<<9, 256, 0, stream>>>(w, wpack, wtap);
    binarize_kernel<<<(N_IMG * HW / 4) / 128, 128, 0, stream>>>(x, scaleA, biasC, apack);
    conv_kernel<<<dim3(2, 7, N_IMG * 32), 256, 0, stream>>>(apack, wpack, wtap, b, out);
}

// Round 3
// 845.148 us; speedup vs baseline: 1.1363x; 1.1363x over previous
//
#include <hip/hip_runtime.h>
#include <hip/hip_bf16.h>
#include <cstdint>

// BN(train) -> sign -> conv3x3(sign(w), pad=1) -> +b -> relu.
// Primary path: i8 XNOR-as-GEMM on MFMA (mfma_i32_32x32x32_i8), zero-padded
// NHWC i8 activations so padding contributes exactly 0.
// Fallback path (small ws): round-2 popcount kernels (known-correct).

#define N_IMG 64
#define C_CH 256
#define HW 3136
#define W_IMG 56
#define NSLICE 16
#define PADW 58
#define PADN 3364            // 58*58
#define MT 128               // pixels (padded-linear) per block
#define TILES_PER_IMG 26     // 26*128 = 3328 >= 3305 (max interior p_pad + 1)
#define STG 246              // staged pixels = MT + 2*59
#define PSTR 264             // LDS byte stride per pixel (66 words: 2-way only)

typedef int v2i __attribute__((ext_vector_type(2)));
typedef int v4i __attribute__((ext_vector_type(4)));
typedef int v16i __attribute__((ext_vector_type(16)));

// ---------------- shared: BN stats ----------------
__global__ void stats_part(const float* __restrict__ x, double2* __restrict__ partial) {
    const int c = blockIdx.x;      // 256
    const int sl = blockIdx.y;     // 16
    const int tid = threadIdx.x;   // 256
    float s = 0.f, q = 0.f;
    for (int n = sl * 4; n < sl * 4 + 4; ++n) {
        const float4* xn = (const float4*)(x + ((size_t)n * C_CH + c) * HW);
        for (int i = tid; i < HW / 4; i += 256) {
            float4 v = xn[i];
            s += (v.x + v.y) + (v.z + v.w);
            q = fmaf(v.x, v.x, q); q = fmaf(v.y, v.y, q);
            q = fmaf(v.z, v.z, q); q = fmaf(v.w, v.w, q);
        }
    }
    double ds = (double)s, dq = (double)q;
#pragma unroll
    for (int off = 32; off > 0; off >>= 1) {
        ds += __shfl_down(ds, off);
        dq += __shfl_down(dq, off);
    }
    __shared__ double sh[4][2];
    int wid = tid >> 6;
    if ((tid & 63) == 0) { sh[wid][0] = ds; sh[wid][1] = dq; }
    __syncthreads();
    if (tid == 0) {
        double S = sh[0][0] + sh[1][0] + sh[2][0] + sh[3][0];
        double Q = sh[0][1] + sh[1][1] + sh[2][1] + sh[3][1];
        partial[sl * C_CH + c] = make_double2(S, Q);
    }
}

__global__ void stats_final(const double2* __restrict__ partial,
                            const float* __restrict__ gamma, const float* __restrict__ beta,
                            float* __restrict__ scaleA, float* __restrict__ biasC) {
    int c = threadIdx.x;   // 256
    double S = 0.0, Q = 0.0;
#pragma unroll
    for (int sl = 0; sl < NSLICE; ++sl) {
        double2 p = partial[sl * C_CH + c];
        S += p.x; Q += p.y;
    }
    const double M = (double)N_IMG * (double)HW;
    double mean = S / M;
    double var = Q / M - mean * mean;
    float inv = (float)(1.0 / sqrt(var + 1e-5));
    float a = gamma[c] * inv;
    scaleA[c] = a;
    biasC[c] = beta[c] - (float)mean * a;
}

// ================= MFMA path =================

// zero the padded i8 activation buffer
__global__ void zero_xq(uint4* __restrict__ p, long n4) {
    long i = (long)blockIdx.x * blockDim.x + threadIdx.x;
    long stride = (long)gridDim.x * blockDim.x;
    for (; i < n4; i += stride) p[i] = make_uint4(0u, 0u, 0u, 0u);
}

// binarize to +1/-1 i8, NHWC padded layout: xq[n][p_pad][c], 4 pixels/thread
__global__ void binarize_i8(const float* __restrict__ x, const float* __restrict__ SA,
                            const float* __restrict__ SC, uint8_t* __restrict__ xq) {
    int t = blockIdx.x * 256 + threadIdx.x;   // 50176 = 200704/4
    if (t >= N_IMG * HW / 4) return;
    int n = t / (HW / 4), r4 = t - n * (HW / 4);
    int rem = r4 * 4, y = rem / W_IMG, x0 = rem - y * W_IMG;   // 4-runs never cross rows
    const float4* xp = (const float4*)(x + (size_t)n * C_CH * HW) + r4;
    uint8_t* dst = xq + ((size_t)n * PADN + (size_t)(y + 1) * PADW + (x0 + 1)) * 256;
#pragma unroll 4
    for (int cg = 0; cg < 16; ++cg) {
        uint32_t w[4][4];
#pragma unroll
        for (int k = 0; k < 4; ++k)
            for (int j = 0; j < 4; ++j) w[k][j] = 0u;
#pragma unroll
        for (int cl = 0; cl < 16; ++cl) {
            int c = cg * 16 + cl;
            float4 v = xp[(size_t)c * (HW / 4)];
            float a = SA[c], cc = SC[c];
            uint32_t b0 = fmaf(a, v.x, cc) > 0.f ? 0x01u : 0xFFu;
            uint32_t b1 = fmaf(a, v.y, cc) > 0.f ? 0x01u : 0xFFu;
            uint32_t b2 = fmaf(a, v.z, cc) > 0.f ? 0x01u : 0xFFu;
            uint32_t b3 = fmaf(a, v.w, cc) > 0.f ? 0x01u : 0xFFu;
            int j = cl >> 2;
            w[0][j] = (w[0][j] >> 8) | (b0 << 24);
            w[1][j] = (w[1][j] >> 8) | (b1 << 24);
            w[2][j] = (w[2][j] >> 8) | (b2 << 24);
            w[3][j] = (w[3][j] >> 8) | (b3 << 24);
        }
#pragma unroll
        for (int k = 0; k < 4; ++k)
            *(uint4*)(dst + (size_t)k * 256 + cg * 16) =
                make_uint4(w[k][0], w[k][1], w[k][2], w[k][3]);
    }
}

// pack sign(w) into B-fragment layout: bq[((t*8+kb)*2+h)*4096 + n*16 + j]
//   = sign(w[n][kb*32+h*16+j][t])
__global__ void wpackB(const float* __restrict__ w, uint8_t* __restrict__ bq) {
    int id = blockIdx.x * 256 + threadIdx.x;   // 36864 = 9*8*2*256
    if (id >= 36864) return;
    int n = id & 255;
    int h = (id >> 8) & 1;
    int kb = (id >> 9) & 7;
    int t = id >> 12;
    uint32_t wds[4] = {0u, 0u, 0u, 0u};
#pragma unroll
    for (int j = 0; j < 16; ++j) {
        int ci = kb * 32 + h * 16 + j;
        float v = w[(size_t)n * 2304 + (size_t)ci * 9 + t];
        uint32_t b = v > 0.f ? 0x01u : 0xFFu;
        wds[j >> 2] = (wds[j >> 2] >> 8) | (b << 24);
    }
    *(uint4*)(bq + (size_t)id * 16) = make_uint4(wds[0], wds[1], wds[2], wds[3]);
}

// implicit-GEMM binary conv. Block: 128 padded-linear pixels x 128 co, 4 waves
// (wave = 64px x 64co = 2x2 mfma tiles). Single LDS stage covers all K.
__global__ __launch_bounds__(256, 2) void conv_mfma(
    const uint8_t* __restrict__ xq, const uint8_t* __restrict__ bq,
    const float* __restrict__ bias, float* __restrict__ out) {
    const int tile = blockIdx.x;                 // 64*26
    const int img = tile / TILES_PER_IMG;
    const int tp = tile - img * TILES_PER_IMG;
    const int n0 = blockIdx.y * 128;
    const int p0 = tp * MT;
    const int tid = threadIdx.x;
    const int lane = tid & 63, wid = tid >> 6;
    const int wave_m = wid & 1, wave_n = wid >> 1;

    __shared__ __align__(16) uint8_t lds[STG * PSTR];   // 64944 B

    // ---- stage [p0-59, p0+187) x 256B ----
    {
        const uint8_t* src = xq + ((size_t)img * PADN + p0 - 59) * 256;
        for (int i = tid; i < STG * 16; i += 256) {
            int px = i >> 4, o = (i & 15) * 16;
            uint4 v = *(const uint4*)(src + (size_t)i * 16);
            uint8_t* d = &lds[px * PSTR + o];
            *(uint2*)d = make_uint2(v.x, v.y);
            *(uint2*)(d + 8) = make_uint2(v.z, v.w);
        }
    }
    __syncthreads();

    const int mrow = lane & 31, khalf = lane >> 5;
    const int abase = (wave_m * 64 + mrow + 59) * PSTR + khalf * 16;
    const uint8_t* bbase = bq + (size_t)khalf * 4096 +
                           (size_t)(n0 + wave_n * 64 + mrow) * 16;

    v16i acc00 = {0}, acc01 = {0}, acc10 = {0}, acc11 = {0};

#pragma unroll
    for (int t = 0; t < 9; ++t) {
        const int offt = (t / 3 - 1) * PADW + (t % 3 - 1);
#pragma unroll
        for (int kb = 0; kb < 8; ++kb) {
            const int ao = abase + offt * PSTR + kb * 32;
            const uint8_t* ap0 = &lds[ao];
            const uint8_t* ap1 = &lds[ao + 32 * PSTR];
            v2i a0l = *(const v2i*)ap0, a0h = *(const v2i*)(ap0 + 8);
            v2i a1l = *(const v2i*)ap1, a1h = *(const v2i*)(ap1 + 8);
            v4i a0 = {a0l.x, a0l.y, a0h.x, a0h.y};
            v4i a1 = {a1l.x, a1l.y, a1h.x, a1h.y};
            const uint8_t* bp = bbase + (size_t)((t * 8 + kb) * 2) * 4096;
            v4i b0 = *(const v4i*)bp;
            v4i b1 = *(const v4i*)(bp + 512);
            acc00 = __builtin_amdgcn_mfma_i32_32x32x32_i8(a0, b0, acc00, 0, 0, 0);
            acc01 = __builtin_amdgcn_mfma_i32_32x32x32_i8(a0, b1, acc01, 0, 0, 0);
            acc10 = __builtin_amdgcn_mfma_i32_32x32x32_i8(a1, b0, acc10, 0, 0, 0);
            acc11 = __builtin_amdgcn_mfma_i32_32x32x32_i8(a1, b1, acc11, 0, 0, 0);
        }
    }

    // ---- epilogue: C/D layout col=lane&31, row=(r&3)+8*(r>>2)+4*(lane>>5) ----
    const int col = mrow;
    const float b0f = bias[n0 + wave_n * 64 + col];
    const float b1f = bias[n0 + wave_n * 64 + 32 + col];
    float* outbase0 = out + ((size_t)img * C_CH + (n0 + wave_n * 64 + col)) * HW;
    float* outbase1 = outbase0 + (size_t)32 * HW;

#pragma unroll
    for (int mt = 0; mt < 2; ++mt) {
        v16i accA = (mt == 0) ? acc00 : acc10;
        v16i accB = (mt == 0) ? acc01 : acc11;
#pragma unroll
        for (int r = 0; r < 16; ++r) {
            int row = (r & 3) + 8 * (r >> 2) + 4 * khalf;
            int p_pad = p0 + wave_m * 64 + mt * 32 + row;
            int yq = p_pad / PADW;           // = y+1
            int xq_ = p_pad - yq * PADW;     // = x+1
            int y = yq - 1, xx = xq_ - 1;
            bool ok = (unsigned)y < 56u && (unsigned)xx < 56u;
            if (ok) {
                int off = y * W_IMG + xx;
                float vA = fmaxf((float)accA[r] + b0f, 0.f);
                float vB = fmaxf((float)accB[r] + b1f, 0.f);
                outbase0[off] = vA;
                outbase1[off] = vB;
            }
        }
    }
}

// ================= fallback path (round-2 popcount, known-correct) =================
__global__ void wpack_kernel(const float* __restrict__ w, uint32_t* __restrict__ wpack,
                             int* __restrict__ wtap) {
    int id = blockIdx.x * 256 + threadIdx.x;
    if (id >= 2304) return;
    int co = id / 9, t = id - co * 9;
    const float* wp = w + (size_t)co * 2304 + t;
    int pc = 0;
#pragma unroll
    for (int wd = 0; wd < 8; ++wd) {
        uint32_t bits = 0;
        for (int i = 0; i < 32; ++i) {
            float v = wp[(size_t)(wd * 32 + i) * 9];
            bits |= (v > 0.f ? (1u << i) : 0u);
        }
        wpack[(size_t)id * 8 + wd] = bits;
        pc += __popc(bits);
    }
    wtap[id] = pc;
}

__global__ void binarize_kernel(const float* __restrict__ x, const float* __restrict__ A,
                                const float* __restrict__ C, uint32_t* __restrict__ apack) {
    int t = blockIdx.x * 128 + threadIdx.x;
    int n = t / (HW / 4);
    int r4 = t - n * (HW / 4);
    const float4* xp = (const float4*)(x + (size_t)n * C_CH * HW) + r4;
    uint32_t bits[4][8];
#pragma unroll
    for (int wo = 0; wo < 8; ++wo) {
        uint32_t b0 = 0, b1 = 0, b2 = 0, b3 = 0;
#pragma unroll
        for (int i = 0; i < 32; ++i) {
            int c = wo * 32 + i;
            float4 v = xp[(size_t)c * (HW / 4)];
            float a = A[c], cc = C[c];
            b0 |= (fmaf(a, v.x, cc) > 0.f ? (1u << i) : 0u);
            b1 |= (fmaf(a, v.y, cc) > 0.f ? (1u << i) : 0u);
            b2 |= (fmaf(a, v.z, cc) > 0.f ? (1u << i) : 0u);
            b3 |= (fmaf(a, v.w, cc) > 0.f ? (1u << i) : 0u);
        }
        bits[0][wo] = b0; bits[1][wo] = b1; bits[2][wo] = b2; bits[3][wo] = b3;
    }
    size_t p0 = (size_t)n * HW + (size_t)r4 * 4;
#pragma unroll
    for (int k = 0; k < 4; ++k) {
        uint4* dst = (uint4*)(apack + (p0 + k) * 8);
        dst[0] = make_uint4(bits[k][0], bits[k][1], bits[k][2], bits[k][3]);
        dst[1] = make_uint4(bits[k][4], bits[k][5], bits[k][6], bits[k][7]);
    }
}

#define COG 8
__global__ __launch_bounds__(256, 6) void conv_kernel(
    const uint32_t* __restrict__ apack, const uint32_t* __restrict__ wpack,
    const int* __restrict__ wtap, const float* __restrict__ bias,
    float* __restrict__ out) {
    const int xt = blockIdx.x, yt = blockIdx.y;
    const int z = blockIdx.z;
    const int n = z >> 5;
    const int cg = z & 31;
    const int tid = threadIdx.x;
    const int tx = tid & 31, ty = tid >> 5;
    const int gx0 = xt * 32, gy0 = yt * 8;
    __shared__ __align__(16) uint32_t ldsb[10 * 34 * 8];
    const int HP = 10 * 34;
    for (int i = tid; i < HP * 2; i += 256) {
        int pix = i >> 1, h = i & 1;
        int r = pix / 34, c0 = pix - r * 34;
        int gy = gy0 - 1 + r, gx = gx0 - 1 + c0;
        uint4 v = make_uint4(0u, 0u, 0u, 0u);
        if (gy >= 0 && gy < W_IMG && gx >= 0 && gx < W_IMG) {
            const uint4* src = (const uint4*)(apack + ((size_t)(n * HW + gy * W_IMG + gx)) * 8);
            v = src[h];
        }
        ((uint4*)ldsb)[pix * 2 + h] = v;
    }
    __syncthreads();
    const uint64_t* l64 = (const uint64_t*)ldsb;
    const uint64_t* w64 = (const uint64_t*)wpack + (size_t)cg * COG * 9 * 4;
    int acc[COG];
#pragma unroll
    for (int co = 0; co < COG; ++co) acc[co] = 0;
#pragma unroll
    for (int dy = 0; dy < 3; ++dy) {
#pragma unroll
        for (int dx = 0; dx < 3; ++dx) {
            const int t = dy * 3 + dx;
            const int p = (ty + dy) * 34 + (tx + dx);
            uint64_t a0 = l64[p * 4 + 0];
            uint64_t a1 = l64[p * 4 + 1];
            uint64_t a2 = l64[p * 4 + 2];
            uint64_t a3 = l64[p * 4 + 3];
#pragma unroll
            for (int co = 0; co < COG; ++co) {
                const uint64_t* wp = w64 + (size_t)(co * 9 + t) * 4;
                int s = acc[co];
                s += __popcll(a0 ^ wp[0]);
                s += __popcll(a1 ^ wp[1]);
                s += __popcll(a2 ^ wp[2]);
                s += __popcll(a3 ^ wp[3]);
                acc[co] = s;
            }
        }
    }
    const int gx = gx0 + tx, gy = gy0 + ty;
    if (gx >= W_IMG) return;
    int vy = 3 - (gy == 0) - (gy == W_IMG - 1);
    int vx = 3 - (gx == 0) - (gx == W_IMG - 1);
    int V = vy * vx;
    int corr[COG];
#pragma unroll
    for (int co = 0; co < COG; ++co) corr[co] = 0;
    if (V != 9) {
#pragma unroll
        for (int t = 0; t < 9; ++t) {
            int dy = t / 3 - 1, dx = t % 3 - 1;
            bool inv = (gy + dy < 0) || (gy + dy > W_IMG - 1) || (gx + dx < 0) || (gx + dx > W_IMG - 1);
            if (inv) {
#pragma unroll
                for (int co = 0; co < COG; ++co) corr[co] += wtap[(cg * COG + co) * 9 + t];
            }
        }
    }
#pragma unroll
    for (int co = 0; co < COG; ++co) {
        int cofull = cg * COG + co;
        float y = (float)(256 * V - 2 * acc[co] + 2 * corr[co]) + bias[cofull];
        out[((size_t)(n * C_CH + cofull)) * HW + gy * W_IMG + gx] = fmaxf(y, 0.f);
    }
}

// ================= launch =================
extern "C" void kernel_launch(void* const* d_in, const int* in_sizes, int n_in,
                              void* d_out, int out_size, void* d_ws, size_t ws_size,
                              hipStream_t stream) {
    const float* x     = (const float*)d_in[0];
    const float* gamma = (const float*)d_in[1];
    const float* beta  = (const float*)d_in[2];
    const float* w     = (const float*)d_in[3];
    const float* b     = (const float*)d_in[4];
    float* out = (float*)d_out;

    char* ws = (char*)d_ws;
    float*    scaleA  = (float*)(ws);
    float*    biasC   = (float*)(ws + 1024);
    double2*  partial = (double2*)(ws + 131072);

    const size_t XQ_OFF = 1u << 20;
    const size_t XQ_BYTES = (size_t)N_IMG * PADN * 256;   // 55,115,776
    const size_t NEED = XQ_OFF + XQ_BYTES + 65536;

    stats_part<<<dim3(C_CH, NSLICE), 256, 0, stream>>>(x, partial);
    stats_final<<<1, C_CH, 0, stream>>>(partial, gamma, beta, scaleA, biasC);

    if (ws_size >= NEED) {
        uint8_t* bq = (uint8_t*)(ws + 196608);            // 589,824 B
        uint8_t* xq = (uint8_t*)(ws + XQ_OFF);
        zero_xq<<<4096, 256, 0, stream>>>((uint4*)xq, (long)(XQ_BYTES / 16));
        wpackB<<<144, 256, 0, stream>>>(w, bq);
        binarize_i8<<<(N_IMG * HW / 4 + 255) / 256, 256, 0, stream>>>(x, scaleA, biasC, xq);
        conv_mfma<<<dim3(N_IMG * TILES_PER_IMG, 2), 256, 0, stream>>>(xq, bq, b, out);
    } else {
        uint32_t* wpack = (uint32_t*)(ws + 2048);
        int*      wtap  = (int*)(ws + 75776);
        uint32_t* apack = (uint32_t*)(ws + 262144);
        wpack_kernel<<<9, 256, 0, stream>>>(w, wpack, wtap);
        binarize_kernel<<<(N_IMG * HW / 4) / 128, 128, 0, stream>>>(x, scaleA, biasC, apack);
        conv_kernel<<<dim3(2, 7, N_IMG * 32), 256, 0, stream>>>(apack, wpack, wtap, b, out);
    }
}

// Round 4
// 573.827 us; speedup vs baseline: 1.6735x; 1.4728x over previous
//
#include <hip/hip_runtime.h>
#include <hip/hip_bf16.h>
#include <cstdint>

// BN(train) -> sign -> conv3x3(sign(w), pad=1) -> +b -> relu.
// i8 XNOR-as-GEMM on mfma_i32_32x32x32_i8 with zero-padded NHWC i8 activations.

#define N_IMG 64
#define C_CH 256
#define HW 3136
#define W_IMG 56
#define NSLICE 32
#define PADW 58
#define PADN 3364            // 58*58
#define MT 64                // pixels (padded-linear) per block
#define TPI 52               // 52*64 = 3328 >= 3305
#define STG 182              // staged pixels = MT + 2*59
#define PSTR 264             // LDS byte stride per pixel (66 words: 2-way only)

typedef int v2i __attribute__((ext_vector_type(2)));
typedef int v4i __attribute__((ext_vector_type(4)));
typedef int v16i __attribute__((ext_vector_type(16)));

// ---------------- BN stats ----------------
__global__ void k_stats1(const float* __restrict__ x, double2* __restrict__ partial) {
    const int c = blockIdx.x;      // 256
    const int sl = blockIdx.y;     // 32 (2 images each)
    const int tid = threadIdx.x;   // 256
    float s = 0.f, q = 0.f;
    for (int n = sl * 2; n < sl * 2 + 2; ++n) {
        const float4* xn = (const float4*)(x + ((size_t)n * C_CH + c) * HW);
        for (int i = tid; i < HW / 4; i += 256) {
            float4 v = xn[i];
            s += (v.x + v.y) + (v.z + v.w);
            q = fmaf(v.x, v.x, q); q = fmaf(v.y, v.y, q);
            q = fmaf(v.z, v.z, q); q = fmaf(v.w, v.w, q);
        }
    }
    double ds = (double)s, dq = (double)q;
#pragma unroll
    for (int off = 32; off > 0; off >>= 1) {
        ds += __shfl_down(ds, off);
        dq += __shfl_down(dq, off);
    }
    __shared__ double sh[4][2];
    int wid = tid >> 6;
    if ((tid & 63) == 0) { sh[wid][0] = ds; sh[wid][1] = dq; }
    __syncthreads();
    if (tid == 0) {
        double S = sh[0][0] + sh[1][0] + sh[2][0] + sh[3][0];
        double Q = sh[0][1] + sh[1][1] + sh[2][1] + sh[3][1];
        partial[sl * C_CH + c] = make_double2(S, Q);
    }
}

__global__ void k_stats2(const double2* __restrict__ partial,
                         const float* __restrict__ gamma, const float* __restrict__ beta,
                         float* __restrict__ scaleA, float* __restrict__ biasC) {
    int c = threadIdx.x;   // 256
    double S = 0.0, Q = 0.0;
#pragma unroll
    for (int sl = 0; sl < NSLICE; ++sl) {
        double2 p = partial[sl * C_CH + c];
        S += p.x; Q += p.y;
    }
    const double M = (double)N_IMG * (double)HW;
    double mean = S / M;
    double var = Q / M - mean * mean;
    float inv = (float)(1.0 / sqrt(var + 1e-5));
    float a = gamma[c] * inv;
    scaleA[c] = a;
    biasC[c] = beta[c] - (float)mean * a;
}

// ---------------- pad-ring zero (3.7 MB) ----------------
__global__ void k_padz(uint8_t* __restrict__ xq) {
    int id = blockIdx.x * 256 + threadIdx.x;        // 233472 = 64*228*16
    if (id >= N_IMG * 228 * 16) return;
    int img = id / (228 * 16);
    int rem = id - img * (228 * 16);
    int r = rem >> 4, off = (rem & 15) * 16;
    int yp, xp;
    if (r < 58)       { yp = 0;      xp = r; }
    else if (r < 116) { yp = 57;     xp = r - 58; }
    else if (r < 172) { yp = r - 115; xp = 0; }
    else              { yp = r - 171; xp = 57; }
    *(uint4*)(xq + ((size_t)img * PADN + yp * PADW + xp) * 256 + off) =
        make_uint4(0u, 0u, 0u, 0u);
}

// ---------------- binarize to +/-1 i8 NHWC padded, LDS transpose ----------------
// grid (49, 64): 64 pixels per block, one image per blockIdx.y
__global__ __launch_bounds__(256) void k_binz(const float* __restrict__ x,
                                              const float* __restrict__ SA,
                                              const float* __restrict__ SC,
                                              uint8_t* __restrict__ xq) {
    const int n = blockIdx.y;
    const int pb = blockIdx.x * 64;
    const int tid = threadIdx.x;
    __shared__ uint8_t lbuf[64 * PSTR];   // 16896 B, [px][c]

    const int p4 = tid & 15;              // pixel quad
    const int cofs = tid >> 4;            // channel offset 0..15
#pragma unroll 4
    for (int c0 = 0; c0 < 256; c0 += 16) {
        int c = c0 + cofs;
        float4 v = *(const float4*)(x + ((size_t)n * C_CH + c) * HW + pb + p4 * 4);
        float a = SA[c], cc = SC[c];
        uint8_t b0 = fmaf(a, v.x, cc) > 0.f ? 0x01 : 0xFF;
        uint8_t b1 = fmaf(a, v.y, cc) > 0.f ? 0x01 : 0xFF;
        uint8_t b2 = fmaf(a, v.z, cc) > 0.f ? 0x01 : 0xFF;
        uint8_t b3 = fmaf(a, v.w, cc) > 0.f ? 0x01 : 0xFF;
        lbuf[(p4 * 4 + 0) * PSTR + c] = b0;
        lbuf[(p4 * 4 + 1) * PSTR + c] = b1;
        lbuf[(p4 * 4 + 2) * PSTR + c] = b2;
        lbuf[(p4 * 4 + 3) * PSTR + c] = b3;
    }
    __syncthreads();
#pragma unroll
    for (int kk = 0; kk < 4; ++kk) {
        int i = tid + kk * 256;
        int px = i >> 4, off = (i & 15) * 16;
        const uint8_t* s = &lbuf[px * PSTR + off];
        uint2 lo = *(const uint2*)s;
        uint2 hi = *(const uint2*)(s + 8);
        int p = pb + px;
        int y = p / W_IMG, xc = p - y * W_IMG;
        uint8_t* d = xq + (((size_t)n * PADN + (y + 1) * PADW + (xc + 1)) * 256 + off);
        *(uint4*)d = make_uint4(lo.x, lo.y, hi.x, hi.y);
    }
}

// ---------------- pack sign(w) into B-fragment layout ----------------
// bq[((t*8+kb)*2+h)*4096 + n*16 + j] = sign(w[n][kb*32+h*16+j][t])
__global__ void k_wpack(const float* __restrict__ w, uint8_t* __restrict__ bq) {
    int id = blockIdx.x * 256 + threadIdx.x;   // 36864 = 9*8*2*256
    if (id >= 36864) return;
    int n = id & 255;
    int h = (id >> 8) & 1;
    int kb = (id >> 9) & 7;
    int t = id >> 12;
    uint32_t wds[4] = {0u, 0u, 0u, 0u};
#pragma unroll
    for (int j = 0; j < 16; ++j) {
        int ci = kb * 32 + h * 16 + j;
        float v = w[(size_t)n * 2304 + (size_t)ci * 9 + t];
        uint32_t b = v > 0.f ? 0x01u : 0xFFu;
        wds[j >> 2] = (wds[j >> 2] >> 8) | (b << 24);
    }
    *(uint4*)(bq + (size_t)id * 16) = make_uint4(wds[0], wds[1], wds[2], wds[3]);
}

// ---------------- implicit-GEMM binary conv ----------------
// Block: 64 px x 256 co, 4 waves (wave = 64px x 64co = 2x2 mfma tiles).
// grid (52, 64). LDS 48 KB -> 3 blocks/CU.
__global__ __launch_bounds__(256, 3) void k_conv(
    const uint8_t* __restrict__ xq, const uint8_t* __restrict__ bq,
    const float* __restrict__ bias, float* __restrict__ out) {
    const int tp = blockIdx.x;                 // 0..51
    const int img = blockIdx.y;                // 0..63
    const int p0 = tp * MT;
    const int tid = threadIdx.x;
    const int lane = tid & 63, wid = tid >> 6;

    __shared__ __align__(16) uint8_t lds[STG * PSTR];   // 48048 B

    // ---- stage [p0-59, p0+123) x 256B, clamped to buffer ----
    {
        const long base_px = (long)img * PADN + p0 - 59;
        const long maxpx = (long)N_IMG * PADN - 1;
        for (int i = tid; i < STG * 16; i += 256) {
            int px = i >> 4, o = (i & 15) * 16;
            long sp = base_px + px;
            sp = sp < 0 ? 0 : (sp > maxpx ? maxpx : sp);
            uint4 v = *(const uint4*)(xq + sp * 256 + o);
            uint8_t* d = &lds[px * PSTR + o];
            *(uint2*)d = make_uint2(v.x, v.y);
            *(uint2*)(d + 8) = make_uint2(v.z, v.w);
        }
    }
    __syncthreads();

    const int mrow = lane & 31, khalf = lane >> 5;
    const int co0 = wid * 64;
    const uint8_t* bbase = bq + (size_t)khalf * 4096 + (size_t)(co0 + mrow) * 16;
    const int abase0 = (mrow + 59) * PSTR + khalf * 16;   // px 0-31
    const int abase1 = (mrow + 91) * PSTR + khalf * 16;   // px 32-63

    v16i acc00 = {0}, acc01 = {0}, acc10 = {0}, acc11 = {0};

    v4i b0 = *(const v4i*)bbase;
    v4i b1 = *(const v4i*)(bbase + 512);

#pragma unroll
    for (int t = 0; t < 9; ++t) {
        const int offt = ((t / 3 - 1) * PADW + (t % 3 - 1)) * PSTR;
#pragma unroll
        for (int kb = 0; kb < 8; ++kb) {
            const int s = t * 8 + kb;
            const int ao = offt + kb * 32;
            const uint8_t* ap0 = &lds[abase0 + ao];
            const uint8_t* ap1 = &lds[abase1 + ao];
            v2i a0l = *(const v2i*)ap0, a0h = *(const v2i*)(ap0 + 8);
            v2i a1l = *(const v2i*)ap1, a1h = *(const v2i*)(ap1 + 8);
            v4i a0 = {a0l.x, a0l.y, a0h.x, a0h.y};
            v4i a1 = {a1l.x, a1l.y, a1h.x, a1h.y};
            // prefetch next step's B
            const int sn = (s < 71) ? s + 1 : 71;
            const uint8_t* bp = bbase + (size_t)sn * 8192;
            v4i nb0 = *(const v4i*)bp;
            v4i nb1 = *(const v4i*)(bp + 512);
            acc00 = __builtin_amdgcn_mfma_i32_32x32x32_i8(a0, b0, acc00, 0, 0, 0);
            acc01 = __builtin_amdgcn_mfma_i32_32x32x32_i8(a0, b1, acc01, 0, 0, 0);
            acc10 = __builtin_amdgcn_mfma_i32_32x32x32_i8(a1, b0, acc10, 0, 0, 0);
            acc11 = __builtin_amdgcn_mfma_i32_32x32x32_i8(a1, b1, acc11, 0, 0, 0);
            b0 = nb0; b1 = nb1;
        }
    }

    // ---- epilogue: LDS transpose -> coalesced pixel-contiguous stores ----
    __syncthreads();
    float* tl = (float*)lds + (size_t)wid * 1056;    // 32x33 floats per wave

#pragma unroll
    for (int ph = 0; ph < 2; ++ph) {
        const int p_pad = p0 + ph * 32 + mrow;
        const int yq = p_pad / PADW;
        const int xc = p_pad - yq * PADW;
        const int y = yq - 1, xx = xc - 1;
        const bool ok = (unsigned)y < 56u && (unsigned)xx < 56u;
        const int ooff = y * W_IMG + xx;
#pragma unroll
        for (int ch = 0; ch < 2; ++ch) {
            v16i A;
            if (ph == 0) A = (ch == 0) ? acc00 : acc01;
            else         A = (ch == 0) ? acc10 : acc11;
            const float bv = bias[co0 + ch * 32 + mrow];
#pragma unroll
            for (int r = 0; r < 16; ++r) {
                int row = (r & 3) + 8 * (r >> 2) + 4 * khalf;
                tl[mrow * 33 + row] = (float)A[r] + bv;
            }
            __syncthreads();
            float* ob = out + ((size_t)img * C_CH + (co0 + ch * 32)) * HW;
#pragma unroll
            for (int rr = 0; rr < 16; ++rr) {
                int co_l = rr * 2 + khalf;
                float v = fmaxf(tl[co_l * 33 + mrow], 0.f);
                if (ok) ob[(size_t)co_l * HW + ooff] = v;
            }
            __syncthreads();
        }
    }
}

// ================= fallback path (round-2 popcount, known-correct) =================
__global__ void wpack_kernel(const float* __restrict__ w, uint32_t* __restrict__ wpack,
                             int* __restrict__ wtap) {
    int id = blockIdx.x * 256 + threadIdx.x;
    if (id >= 2304) return;
    int co = id / 9, t = id - co * 9;
    const float* wp = w + (size_t)co * 2304 + t;
    int pc = 0;
#pragma unroll
    for (int wd = 0; wd < 8; ++wd) {
        uint32_t bits = 0;
        for (int i = 0; i < 32; ++i) {
            float v = wp[(size_t)(wd * 32 + i) * 9];
            bits |= (v > 0.f ? (1u << i) : 0u);
        }
        wpack[(size_t)id * 8 + wd] = bits;
        pc += __popc(bits);
    }
    wtap[id] = pc;
}

__global__ void binarize_kernel(const float* __restrict__ x, const float* __restrict__ A,
                                const float* __restrict__ C, uint32_t* __restrict__ apack) {
    int t = blockIdx.x * 128 + threadIdx.x;
    int n = t / (HW / 4);
    int r4 = t - n * (HW / 4);
    const float4* xp = (const float4*)(x + (size_t)n * C_CH * HW) + r4;
    uint32_t bits[4][8];
#pragma unroll
    for (int wo = 0; wo < 8; ++wo) {
        uint32_t b0 = 0, b1 = 0, b2 = 0, b3 = 0;
#pragma unroll
        for (int i = 0; i < 32; ++i) {
            int c = wo * 32 + i;
            float4 v = xp[(size_t)c * (HW / 4)];
            float a = A[c], cc = C[c];
            b0 |= (fmaf(a, v.x, cc) > 0.f ? (1u << i) : 0u);
            b1 |= (fmaf(a, v.y, cc) > 0.f ? (1u << i) : 0u);
            b2 |= (fmaf(a, v.z, cc) > 0.f ? (1u << i) : 0u);
            b3 |= (fmaf(a, v.w, cc) > 0.f ? (1u << i) : 0u);
        }
        bits[0][wo] = b0; bits[1][wo] = b1; bits[2][wo] = b2; bits[3][wo] = b3;
    }
    size_t p0 = (size_t)n * HW + (size_t)r4 * 4;
#pragma unroll
    for (int k = 0; k < 4; ++k) {
        uint4* dst = (uint4*)(apack + (p0 + k) * 8);
        dst[0] = make_uint4(bits[k][0], bits[k][1], bits[k][2], bits[k][3]);
        dst[1] = make_uint4(bits[k][4], bits[k][5], bits[k][6], bits[k][7]);
    }
}

#define COG 8
__global__ __launch_bounds__(256, 6) void conv_kernel(
    const uint32_t* __restrict__ apack, const uint32_t* __restrict__ wpack,
    const int* __restrict__ wtap, const float* __restrict__ bias,
    float* __restrict__ out) {
    const int xt = blockIdx.x, yt = blockIdx.y;
    const int z = blockIdx.z;
    const int n = z >> 5;
    const int cg = z & 31;
    const int tid = threadIdx.x;
    const int tx = tid & 31, ty = tid >> 5;
    const int gx0 = xt * 32, gy0 = yt * 8;
    __shared__ __align__(16) uint32_t ldsb[10 * 34 * 8];
    const int HP = 10 * 34;
    for (int i = tid; i < HP * 2; i += 256) {
        int pix = i >> 1, h = i & 1;
        int r = pix / 34, c0 = pix - r * 34;
        int gy = gy0 - 1 + r, gx = gx0 - 1 + c0;
        uint4 v = make_uint4(0u, 0u, 0u, 0u);
        if (gy >= 0 && gy < W_IMG && gx >= 0 && gx < W_IMG) {
            const uint4* src = (const uint4*)(apack + ((size_t)(n * HW + gy * W_IMG + gx)) * 8);
            v = src[h];
        }
        ((uint4*)ldsb)[pix * 2 + h] = v;
    }
    __syncthreads();
    const uint64_t* l64 = (const uint64_t*)ldsb;
    const uint64_t* w64 = (const uint64_t*)wpack + (size_t)cg * COG * 9 * 4;
    int acc[COG];
#pragma unroll
    for (int co = 0; co < COG; ++co) acc[co] = 0;
#pragma unroll
    for (int dy = 0; dy < 3; ++dy) {
#pragma unroll
        for (int dx = 0; dx < 3; ++dx) {
            const int t = dy * 3 + dx;
            const int p = (ty + dy) * 34 + (tx + dx);
            uint64_t a0 = l64[p * 4 + 0];
            uint64_t a1 = l64[p * 4 + 1];
            uint64_t a2 = l64[p * 4 + 2];
            uint64_t a3 = l64[p * 4 + 3];
#pragma unroll
            for (int co = 0; co < COG; ++co) {
                const uint64_t* wp = w64 + (size_t)(co * 9 + t) * 4;
                int s = acc[co];
                s += __popcll(a0 ^ wp[0]);
                s += __popcll(a1 ^ wp[1]);
                s += __popcll(a2 ^ wp[2]);
                s += __popcll(a3 ^ wp[3]);
                acc[co] = s;
            }
        }
    }
    const int gx = gx0 + tx, gy = gy0 + ty;
    if (gx >= W_IMG) return;
    int vy = 3 - (gy == 0) - (gy == W_IMG - 1);
    int vx = 3 - (gx == 0) - (gx == W_IMG - 1);
    int V = vy * vx;
    int corr[COG];
#pragma unroll
    for (int co = 0; co < COG; ++co) corr[co] = 0;
    if (V != 9) {
#pragma unroll
        for (int t = 0; t < 9; ++t) {
            int dy = t / 3 - 1, dx = t % 3 - 1;
            bool inv = (gy + dy < 0) || (gy + dy > W_IMG - 1) || (gx + dx < 0) || (gx + dx > W_IMG - 1);
            if (inv) {
#pragma unroll
                for (int co = 0; co < COG; ++co) corr[co] += wtap[(cg * COG + co) * 9 + t];
            }
        }
    }
#pragma unroll
    for (int co = 0; co < COG; ++co) {
        int cofull = cg * COG + co;
        float y = (float)(256 * V - 2 * acc[co] + 2 * corr[co]) + bias[cofull];
        out[((size_t)(n * C_CH + cofull)) * HW + gy * W_IMG + gx] = fmaxf(y, 0.f);
    }
}

// ================= launch =================
extern "C" void kernel_launch(void* const* d_in, const int* in_sizes, int n_in,
                              void* d_out, int out_size, void* d_ws, size_t ws_size,
                              hipStream_t stream) {
    const float* x     = (const float*)d_in[0];
    const float* gamma = (const float*)d_in[1];
    const float* beta  = (const float*)d_in[2];
    const float* w     = (const float*)d_in[3];
    const float* b     = (const float*)d_in[4];
    float* out = (float*)d_out;

    char* ws = (char*)d_ws;
    float*    scaleA  = (float*)(ws);
    float*    biasC   = (float*)(ws + 1024);
    double2*  partial = (double2*)(ws + 4096);        // 131072 B

    const size_t XQ_OFF = 1u << 20;
    const size_t XQ_BYTES = (size_t)N_IMG * PADN * 256;   // 55,115,776
    const size_t NEED = XQ_OFF + XQ_BYTES;

    k_stats1<<<dim3(C_CH, NSLICE), 256, 0, stream>>>(x, partial);
    k_stats2<<<1, C_CH, 0, stream>>>(partial, gamma, beta, scaleA, biasC);

    if (ws_size >= NEED) {
        uint8_t* bq = (uint8_t*)(ws + 196608);            // 589,824 B
        uint8_t* xq = (uint8_t*)(ws + XQ_OFF);
        k_padz<<<(N_IMG * 228 * 16 + 255) / 256, 256, 0, stream>>>(xq);
        k_wpack<<<144, 256, 0, stream>>>(w, bq);
        k_binz<<<dim3(49, N_IMG), 256, 0, stream>>>(x, scaleA, biasC, xq);
        k_conv<<<dim3(TPI, N_IMG), 256, 0, stream>>>(xq, bq, b, out);
    } else {
        uint32_t* wpack = (uint32_t*)(ws + 2048);
        int*      wtap  = (int*)(ws + 135168);
        uint32_t* apack = (uint32_t*)(ws + 262144);
        wpack_kernel<<<9, 256, 0, stream>>>(w, wpack, wtap);
        binarize_kernel<<<(N_IMG * HW / 4) / 128, 128, 0, stream>>>(x, scaleA, biasC, apack);
        conv_kernel<<<dim3(2, 7, N_IMG * 32), 256, 0, stream>>>(apack, wpack, wtap, b, out);
    }
}